// Round 9
// baseline (597.349 us; speedup 1.0000x reference)
//
#include <hip/hip_runtime.h>
#include <hip/hip_fp16.h>

// LightGCN propagation, round 9 (= round 7/8 resubmitted; GPU acquisition
// timed out both times, kernel never ran).
// r6 post-mortem: aggs are fabric-BW-proportional (3.6-3.9 TB/s effective at
// both fp16 and fp8 volumes) -> near byte-floor at 3x90us. The other ~174us
// is binA's per-edge double LDS-atomic pass (~78us of VALU/LDS) + binB's
// 147-block underutilization.
// This round: direct global-atomic-cursor binning (no LDS histogram). The
// shared cursor makes binbuf writes cluster at ~293 frontier lines ->
// STRUCTURAL write locality (r3 lesson). BIN_SZ 1024->512 doubles binB grid.

#define N_USERS 100000
#define N_ITEMS 50000
#define N_NODES 150000
#define DIM 128
#define N_EDGES 3000000
#define CAP 64              // padded CSR capacity; deg ~ Poisson(20), max ~45

#define SCALE 8192.0f       // fp8 global scale: max |x|*8192 ~ 90 << 448
#define INV_SCALE (1.0f / 8192.0f)

#define BIN_SHIFT 9
#define BIN_SZ 512                                    // nodes per bin
#define NBINS ((N_NODES + BIN_SZ - 1) / BIN_SZ)       // 293
#define CAPB 11776          // per-bin capacity; mean 10240, sigma ~101 (+15s)
#define CNT_PAD 32          // bincnt counters 128B apart (line-private)

#define EDGE_BLOCKS 2048
#define CONV_THREADS (N_NODES * 16)                   // one thread per 8 floats
#define CONV_BLOCKS ((CONV_THREADS + 255) / 256)      // 9375

static inline size_t align_up(size_t x, size_t a) { return (x + a - 1) & ~(a - 1); }

// ---------- fp8 e4m3 helpers (hw cvt primary, sw fallback keeps compile safe) ----------
typedef float v2f __attribute__((ext_vector_type(2)));

#if defined(__has_builtin)
#if __has_builtin(__builtin_amdgcn_cvt_pk_f32_fp8) && __has_builtin(__builtin_amdgcn_cvt_pk_fp8_f32)
#define FP8_HW 1
#endif
#endif

__device__ __forceinline__ v2f fp8x2_dec(int q) {          // bytes 0,1 -> 2 floats
#ifdef FP8_HW
    return __builtin_amdgcn_cvt_pk_f32_fp8(q, false);
#else
    v2f r;
    #pragma unroll
    for (int i = 0; i < 2; ++i) {
        int b = (q >> (8 * i)) & 0xFF;
        int e = (b >> 3) & 15, m = b & 7;
        float mag = e ? ldexpf((float)(8 + m), e - 10) : ldexpf((float)m, -9);
        ((float*)&r)[i] = (b & 0x80) ? -mag : mag;
    }
    return r;
#endif
}

__device__ __forceinline__ int fp8_enc1(float v) {         // sw single-byte encode
    int s = v < 0.f ? 0x80 : 0;
    float a = fabsf(v);
    if (a > 448.f) a = 448.f;
    int byte;
    if (a < 0.015625f) {
        int q = (int)(a * 512.f + 0.5f);
        byte = q;
    } else {
        int e; float fr = frexpf(a, &e);
        int E = e - 1;
        int m = (int)((fr * 2.f - 1.f) * 8.f + 0.5f);
        if (m == 8) { m = 0; ++E; }
        if (E > 8) { E = 8; m = 7; }
        byte = ((E + 7) << 3) | m;
    }
    return byte | s;
}

__device__ __forceinline__ int fp8x2_enc(float x, float y) {
#ifdef FP8_HW
    return __builtin_amdgcn_cvt_pk_fp8_f32(x, y, 0, false);
#else
    return fp8_enc1(x) | (fp8_enc1(y) << 8);
#endif
}

__device__ __forceinline__ int fp8x4_enc(float a, float b, float c, float d) {
#ifdef FP8_HW
    int p = __builtin_amdgcn_cvt_pk_fp8_f32(a, b, 0, false);
    return __builtin_amdgcn_cvt_pk_fp8_f32(c, d, p, true);
#else
    return fp8_enc1(a) | (fp8_enc1(b) << 8) | (fp8_enc1(c) << 16) | (fp8_enc1(d) << 24);
#endif
}

// ---------- Pass A: direct cursor binning; extra blocks convert x -> fp8 ----------
__global__ __launch_bounds__(256) void binA_conv_kernel(
    const int* __restrict__ src, const int* __restrict__ dst,
    unsigned int* __restrict__ binbuf, int* __restrict__ bincnt,
    const float4* __restrict__ u4, const float4* __restrict__ i4,
    uint2* __restrict__ xq8) {
    if (blockIdx.x < EDGE_BLOCKS) {
        int stride = EDGE_BLOCKS * 256;
        for (int i = blockIdx.x * 256 + threadIdx.x; i < N_EDGES; i += stride) {
            int d = dst[i], s = src[i];
            int bin = d >> BIN_SHIFT;
            int pos = atomicAdd(&bincnt[bin * CNT_PAD], 1);
            if (pos < CAPB)
                binbuf[(size_t)bin * CAPB + pos] =
                    ((unsigned)(d & (BIN_SZ - 1)) << 18) | (unsigned)s;
        }
    } else {
        int t = (int)(blockIdx.x - EDGE_BLOCKS) * 256 + threadIdx.x;  // 8 floats each
        if (t < CONV_THREADS) {
            int fi = t * 2;                       // float4 index
            float4 a, b;
            if (fi < N_USERS * 32) { a = u4[fi]; b = u4[fi + 1]; }
            else { a = i4[fi - N_USERS * 32]; b = i4[fi - N_USERS * 32 + 1]; }
            uint2 v;
            v.x = (unsigned)fp8x4_enc(a.x * SCALE, a.y * SCALE, a.z * SCALE, a.w * SCALE);
            v.y = (unsigned)fp8x4_enc(b.x * SCALE, b.y * SCALE, b.z * SCALE, b.w * SCALE);
            xq8[t] = v;
        }
    }
}

// ---------- Pass B: one block per bin; cnt in LDS; L2-windowed slot scatter ----------
__global__ __launch_bounds__(512) void binB_kernel(
    const unsigned int* __restrict__ binbuf, const int* __restrict__ bincnt,
    int* __restrict__ cnt, int* __restrict__ slots) {
    __shared__ int s_cnt[BIN_SZ];
    int b = blockIdx.x;
    s_cnt[threadIdx.x] = 0;
    __syncthreads();
    int n = min(bincnt[b * CNT_PAD], CAPB);
    const unsigned int* buf = binbuf + (size_t)b * CAPB;
    int nodebase = b << BIN_SHIFT;
    for (int i = threadIdx.x; i < n; i += 512) {
        unsigned pk = buf[i];
        int s  = (int)(pk & 0x3FFFFu);
        int dl = (int)(pk >> 18);
        int pos = atomicAdd(&s_cnt[dl], 1);
        if (pos < CAP) slots[(size_t)(nodebase + dl) * CAP + pos] = s;
    }
    __syncthreads();
    int node = nodebase + (int)threadIdx.x;
    if (node < N_NODES) cnt[node] = s_cnt[threadIdx.x];   // full in-degree
}

// ---------- aggregate: one wave per dst node; 64 lanes x fp8x2 = 128B/edge ----------
// LAYER 1: gather xq  -> write a1q, total_h  = a1
// LAYER 2: gather a1q -> write a2q, total_h += a2
// LAYER 3: gather a2q -> out = 0.25*(x_f32 + total_h + a3)
template <int LAYER>
__global__ __launch_bounds__(256) void agg_kernel(
    const unsigned short* __restrict__ accin, const int* __restrict__ slots,
    const int* __restrict__ cnt, unsigned short* __restrict__ accout,
    __half2* __restrict__ total_h,
    const float2* __restrict__ u2, const float2* __restrict__ i2,
    float2* __restrict__ out) {
    int node = (blockIdx.x << 2) + (threadIdx.x >> 6);
    if (node >= N_NODES) return;
    int lane = threadIdx.x & 63;
    int deg = cnt[node];
    int n = min(deg, CAP);
    int myslot = slots[node * CAP + lane];   // lane < CAP: always in-bounds
    float sx = 0.f, sy = 0.f;
    int k = 0;
    for (; k + 8 <= n; k += 8) {             // 8 independent 128B gathers in flight
        int q0 = accin[__shfl(myslot, k)     * 64 + lane];
        int q1 = accin[__shfl(myslot, k + 1) * 64 + lane];
        int q2 = accin[__shfl(myslot, k + 2) * 64 + lane];
        int q3 = accin[__shfl(myslot, k + 3) * 64 + lane];
        int q4 = accin[__shfl(myslot, k + 4) * 64 + lane];
        int q5 = accin[__shfl(myslot, k + 5) * 64 + lane];
        int q6 = accin[__shfl(myslot, k + 6) * 64 + lane];
        int q7 = accin[__shfl(myslot, k + 7) * 64 + lane];
        v2f v0 = fp8x2_dec(q0), v1 = fp8x2_dec(q1), v2 = fp8x2_dec(q2), v3 = fp8x2_dec(q3);
        v2f v4 = fp8x2_dec(q4), v5 = fp8x2_dec(q5), v6 = fp8x2_dec(q6), v7 = fp8x2_dec(q7);
        sx += ((v0.x + v1.x) + (v2.x + v3.x)) + ((v4.x + v5.x) + (v6.x + v7.x));
        sy += ((v0.y + v1.y) + (v2.y + v3.y)) + ((v4.y + v5.y) + (v6.y + v7.y));
    }
    for (; k + 2 <= n; k += 2) {
        v2f v0 = fp8x2_dec(accin[__shfl(myslot, k)     * 64 + lane]);
        v2f v1 = fp8x2_dec(accin[__shfl(myslot, k + 1) * 64 + lane]);
        sx += v0.x + v1.x;
        sy += v0.y + v1.y;
    }
    if (k < n) {
        v2f v = fp8x2_dec(accin[__shfl(myslot, k) * 64 + lane]);
        sx += v.x; sy += v.y;
    }
    float w = deg > 0 ? 1.0f / (float)deg : 0.0f;
    float ax = sx * w, ay = sy * w;          // scaled layer output (= a * SCALE)
    int oi = node * 64 + lane;
    if (LAYER < 3) {
        accout[oi] = (unsigned short)(fp8x2_enc(ax, ay) & 0xFFFF);
        float cx = ax * INV_SCALE, cy = ay * INV_SCALE;
        if (LAYER == 1) {
            total_h[oi] = __float22half2_rn(make_float2(cx, cy));
        } else {
            float2 t = __half22float2(total_h[oi]);
            total_h[oi] = __float22half2_rn(make_float2(t.x + cx, t.y + cy));
        }
    } else {
        float2 xv = (node < N_USERS) ? u2[oi] : i2[oi - N_USERS * 64];
        float2 t = __half22float2(total_h[oi]);
        float2 o;
        o.x = (xv.x + t.x + ax * INV_SCALE) * 0.25f;
        o.y = (xv.y + t.y + ay * INV_SCALE) * 0.25f;
        out[oi] = o;
    }
}

extern "C" void kernel_launch(void* const* d_in, const int* in_sizes, int n_in,
                              void* d_out, int out_size, void* d_ws, size_t ws_size,
                              hipStream_t stream) {
    const float* user_emb = (const float*)d_in[0];
    const float* item_emb = (const float*)d_in[1];
    const int*   edge     = (const int*)d_in[2];   // [2, N_EDGES]
    const int*   e_src    = edge;                  // row 0: message source
    const int*   e_dst    = edge + N_EDGES;        // row 1: aggregation target
    float* out = (float*)d_out;

    // ---- workspace carve (~148.8 MB; 168 MB proven available in r1) ----
    char* p = (char*)d_ws;
    int*            cnt    = (int*)p;            p += align_up((size_t)N_NODES * 4, 512);
    int*            slots  = (int*)p;            p += align_up((size_t)N_NODES * CAP * 4, 512);
    unsigned short* xq     = (unsigned short*)p; p += align_up((size_t)N_NODES * 128, 512);
    unsigned short* a1q    = (unsigned short*)p; p += align_up((size_t)N_NODES * 128, 512);
    unsigned short* a2q    = (unsigned short*)p; p += align_up((size_t)N_NODES * 128, 512);
    __half2*        th     = (__half2*)p;        p += align_up((size_t)N_NODES * 64 * 4, 512);
    unsigned*       binbuf = (unsigned*)p;       p += align_up((size_t)NBINS * CAPB * 4, 512);
    int*            bincnt = (int*)p;            p += align_up((size_t)NBINS * CNT_PAD * 4, 512);
    if ((size_t)(p - (char*)d_ws) > ws_size) return;

    const float2* u2 = (const float2*)user_emb;
    const float2* i2 = (const float2*)item_emb;

    hipMemsetAsync(bincnt, 0, (size_t)NBINS * CNT_PAD * 4, stream);
    binA_conv_kernel<<<EDGE_BLOCKS + CONV_BLOCKS, 256, 0, stream>>>(
        e_src, e_dst, binbuf, bincnt,
        (const float4*)user_emb, (const float4*)item_emb, (uint2*)xq);
    binB_kernel<<<NBINS, 512, 0, stream>>>(binbuf, bincnt, cnt, slots);

    int agg_grid = (N_NODES + 3) / 4;
    agg_kernel<1><<<agg_grid, 256, 0, stream>>>(xq,  slots, cnt, a1q, th, u2, i2, nullptr);
    agg_kernel<2><<<agg_grid, 256, 0, stream>>>(a1q, slots, cnt, a2q, th, u2, i2, nullptr);
    agg_kernel<3><<<agg_grid, 256, 0, stream>>>(a2q, slots, cnt, nullptr, th, u2, i2, (float2*)out);
}